// Round 4
// baseline (446.171 us; speedup 1.0000x reference)
//
#include <hip/hip_runtime.h>

// Problem constants (fixed by the reference): E=8, M=32768, K=1024, N=1024
#define M_DIM 32768
#define K_DIM 1024
#define N_DIM 1024
#define E_NUM 8

#define BM 128
#define BN 128
#define BK 64             // k-bytes staged per step (was 128: 64KB LDS -> 2 blk/CU, m132's mistake)
#define KSTEPS (K_DIM / BK)   // 16

typedef __attribute__((ext_vector_type(4))) int v4i;

// ---------------------------------------------------------------------------
// Pass 1a: pack x (int32 valued int8) -> int8 [M][K].  (unchanged)
// ---------------------------------------------------------------------------
__global__ __launch_bounds__(256) void pack_x_kernel(const int4* __restrict__ x,
                                                     int* __restrict__ xq) {
    const int base = blockIdx.x * 1024 + (threadIdx.x >> 6) * 256 + (threadIdx.x & 63);
#pragma unroll
    for (int k = 0; k < 4; ++k) {
        const int4 a = x[base + k * 64];
        xq[base + k * 64] =
            (a.x & 255) | ((a.y & 255) << 8) | ((a.z & 255) << 16) | (a.w << 24);
    }
}

// ---------------------------------------------------------------------------
// Pass 1b: pack + transpose weight [E][K][N] int32 -> [E][N][K] int8.
// (unchanged)
// ---------------------------------------------------------------------------
__global__ __launch_bounds__(256) void pack_wt_kernel(const int* __restrict__ w,
                                                      int* __restrict__ wt) {
    __shared__ signed char tile[64][260];   // [n][k], +4 pad keeps banks spread
    const int e    = blockIdx.z;
    const int n0   = blockIdx.x * 64;
    const int k0   = blockIdx.y * 256;
    const int tid  = threadIdx.x;
    const int lane = tid & 63;
    const int wv   = tid >> 6;

    const int* wp = w + ((size_t)e << 20);
#pragma unroll 4
    for (int i = 0; i < 64; ++i) {
        const int k = wv * 64 + i;          // each wave: 64 k-rows
        tile[lane][k] = (signed char)wp[(size_t)(k0 + k) * N_DIM + n0 + lane];
    }
    __syncthreads();

    int* wo = wt + ((size_t)e << 18);       // int units: 1MB/4 per expert
#pragma unroll
    for (int i = 0; i < 16; ++i) {
        const int n = i * 4 + wv;
        const int v = *(const int*)&tile[n][lane * 4];   // 260 % 4 == 0, aligned
        wo[(size_t)(n0 + n) * (K_DIM / 4) + (k0 >> 2) + lane] = v;
    }
}

// ---------------------------------------------------------------------------
// Pass 2: grouped int8 GEMM + fused dequant.
// Round-4: REVERT to round-2 sync structure (round-3 fragment pipelining:
// -43%, +64MiB scratch-spill writes + m141 sched_barrier pinning). One
// lever: occupancy. BK=64 dbuf (2x8KB A + 2x8KB B = 32KB LDS) + direct
// epilogue stores (no LDS bounce) -> 4 blocks/CU, 16 waves/CU (was 2/8).
// Barrier dead time of one block now overlapped by 3 other blocks (m114).
// Counted vmcnt kept: stage = 4 loads, steady-state wait = vmcnt(4).
// ---------------------------------------------------------------------------
__global__ __launch_bounds__(256, 4) void gmm_kernel(
    const signed char* __restrict__ xq,    // [M][K] int8
    const signed char* __restrict__ wtq,   // [E][N][K] int8
    const float* __restrict__ scale,       // [E][N]
    const float* __restrict__ pts,         // [M]
    const int* __restrict__ g32,           // group_list viewed as int32
    float* __restrict__ out)               // [M][N] fp32
{
    // A(b) = smem + b*8KB, B(b) = smem + 16KB + b*8KB
    __shared__ signed char smem[32768];

    const int tid  = threadIdx.x;
    const int lane = tid & 63;
    const int wv   = tid >> 6;             // wave 0..3
    const int gid  = blockIdx.x;

    // XCD-stripe mapping: xcd = gid&7 owns contiguous 4096 m-rows, n inner
    // -> per-XCD A working set 4MB (L2-resident). FETCH 166->58MB confirmed.
    const int xcd   = gid & 7;
    const int local = gid >> 3;
    const int m0    = (xcd * 32 + (local >> 3)) * BM;
    const int n0    = (local & 7) * BN;

    // group_list (dtype-robust)
    const bool g_is_i64 = (g32[7] != M_DIM);
    int cum[E_NUM];
#pragma unroll
    for (int e = 0; e < E_NUM; ++e)
        cum[e] = g_is_i64 ? g32[2 * e] : g32[e];
    int e0 = 0;
    while (e0 < E_NUM - 1 && cum[e0] <= m0) ++e0;
    int e1 = 0;
    while (e1 < E_NUM - 1 && cum[e1] <= m0 + BM - 1) ++e1;

    const int wm    = (wv >> 1) * 64;
    const int wn    = (wv & 1) * 64;
    const int row_a = lane & 15;
    const int quad  = lane >> 4;
    // fragment k-slot swizzle: global slot q of row r lives at LDS slot q^(r&3)
    const int sa    = (quad ^ (row_a & 3)) * 16;    // row_a&3 == r&3 for all frag rows

    // staging lane geometry: wave covers 16 rows x 64B = 1KB per instr
    const int st_r = lane >> 2;                     // row in wave-chunk 0..15
    const int st_c = ((lane & 3) ^ (st_r & 3)) * 16; // swizzled source slot

    const signed char* xg = xq + (size_t)m0 * K_DIM;

    for (int e = e0; e <= e1; ++e) {
        const int lo = (e == 0) ? 0 : cum[e - 1];
        const int hi = cum[e];
        if (hi <= lo) continue;            // block-uniform
        const int slo = lo > m0 ? lo : m0;
        const int shi = hi < m0 + BM ? hi : m0 + BM;
        if (slo >= shi) continue;

        const signed char* wg = wtq + ((size_t)e << 20) + (size_t)n0 * K_DIM;

        // epilogue scalars (fly during the whole GEMM)
        float sc[4], pt[16];
#pragma unroll
        for (int j = 0; j < 4; ++j)
            sc[j] = scale[e * N_DIM + n0 + wn + j * 16 + row_a];
#pragma unroll
        for (int i = 0; i < 4; ++i)
#pragma unroll
            for (int r = 0; r < 4; ++r)
                pt[i * 4 + r] = pts[m0 + wm + i * 16 + quad * 4 + r];

        v4i acc[4][4];
#pragma unroll
        for (int i = 0; i < 4; ++i)
#pragma unroll
            for (int j = 0; j < 4; ++j)
                acc[i][j] = (v4i){0, 0, 0, 0};

        auto stage = [&](int t, int b) {   // 4 global_load_lds per thread
            const int kb = t * BK;
            signed char* Ad = smem + b * 8192;
            signed char* Bd = smem + 16384 + b * 8192;
#pragma unroll
            for (int g = 0; g < 2; ++g) {
                const int row = g * 64 + wv * 16 + st_r;   // 0..127
                __builtin_amdgcn_global_load_lds(
                    (const __attribute__((address_space(1))) void*)
                        (xg + (size_t)row * K_DIM + kb + st_c),
                    (__attribute__((address_space(3))) void*)(Ad + g * 4096 + wv * 1024),
                    16, 0, 0);
                __builtin_amdgcn_global_load_lds(
                    (const __attribute__((address_space(1))) void*)
                        (wg + (size_t)row * K_DIM + kb + st_c),
                    (__attribute__((address_space(3))) void*)(Bd + g * 4096 + wv * 1024),
                    16, 0, 0);
            }
        };

        // prologue: two tiles in flight, wait only for tile 0
        stage(0, 0);
        stage(1, 1);
        asm volatile("s_waitcnt vmcnt(4)" ::: "memory");   // my tile-0 loads done
        __builtin_amdgcn_sched_barrier(0);
        __builtin_amdgcn_s_barrier();                      // everyone's tile 0 in LDS

        for (int t = 0; t < KSTEPS; ++t) {
            const int cur = t & 1;
            const signed char* Ab = smem + cur * 8192;
            const signed char* Bb = smem + 16384 + cur * 8192;

            v4i af[4], bf[4];
#pragma unroll
            for (int i = 0; i < 4; ++i)
                af[i] = *(const v4i*)(Ab + (wm + i * 16 + row_a) * BK + sa);
#pragma unroll
            for (int j = 0; j < 4; ++j)
                bf[j] = *(const v4i*)(Bb + (wn + j * 16 + row_a) * BK + sa);
#pragma unroll
            for (int i = 0; i < 4; ++i)
#pragma unroll
                for (int j = 0; j < 4; ++j)
                    acc[i][j] = __builtin_amdgcn_mfma_i32_16x16x64_i8(
                        af[i], bf[j], acc[i][j], 0, 0, 0);

            // all DS reads from buf cur complete -> cur free for overwrite
            asm volatile("s_waitcnt lgkmcnt(0)" ::: "memory");
            __builtin_amdgcn_sched_barrier(0);
            __builtin_amdgcn_s_barrier();                // all waves done w/ cur

            if (t + 2 < KSTEPS) stage(t + 2, cur);       // refill freed buffer
            if (t + 1 < KSTEPS) {
                if (t + 2 < KSTEPS)
                    asm volatile("s_waitcnt vmcnt(4)" ::: "memory"); // t+1 landed
                else
                    asm volatile("s_waitcnt vmcnt(0)" ::: "memory"); // last tile
                __builtin_amdgcn_sched_barrier(0);
                __builtin_amdgcn_s_barrier();            // visible to all waves
            }
        }

        // epilogue: dequant + segment-masked direct stores (no LDS bounce:
        // WRITE_SIZE measured identical with/without; keeps LDS at 32KB)
#pragma unroll
        for (int i = 0; i < 4; ++i) {
            const int rb = m0 + wm + i * 16 + quad * 4;
#pragma unroll
            for (int j = 0; j < 4; ++j) {
                const int c = n0 + wn + j * 16 + row_a;
#pragma unroll
                for (int r = 0; r < 4; ++r) {
                    const int rr = rb + r;
                    if (rr >= slo && rr < shi)
                        out[(size_t)rr * N_DIM + c] =
                            (float)acc[i][j][r] * sc[j] * pt[i * 4 + r];
                }
            }
        }
        // NOTE: stores count in vmcnt, but they precede the next expert's
        // stage loads in issue order, so the prologue vmcnt(4) still
        // guarantees the 4 tile-0 loads retired (in-order counting).
    }
}

// ---------------------------------------------------------------------------
extern "C" void kernel_launch(void* const* d_in, const int* in_sizes, int n_in,
                              void* d_out, int out_size, void* d_ws, size_t ws_size,
                              hipStream_t stream) {
    const int*   x     = (const int*)d_in[0];
    const int*   w     = (const int*)d_in[1];
    const float* scale = (const float*)d_in[2];
    const float* pts   = (const float*)d_in[3];
    const int*   g32   = (const int*)d_in[4];   // int32 or int64 -- sniffed in-kernel
    float*       out   = (float*)d_out;

    signed char* xq  = (signed char*)d_ws;                 // 32 MB
    signed char* wtq = xq + (size_t)M_DIM * K_DIM;         // 8 MB

    pack_x_kernel<<<M_DIM * K_DIM / 4 / 1024, 256, 0, stream>>>(
        (const int4*)x, (int*)xq);

    pack_wt_kernel<<<dim3(N_DIM / 64, K_DIM / 256, E_NUM), 256, 0, stream>>>(
        w, (int*)wtq);

    gmm_kernel<<<(M_DIM / BM) * (N_DIM / BN), 256, 0, stream>>>(
        xq, wtq, scale, pts, g32, out);
}

// Round 7
// 320.505 us; speedup vs baseline: 1.3921x; 1.3921x over previous
//
#include <hip/hip_runtime.h>

// Problem constants (fixed by the reference): E=8, M=32768, K=1024, N=1024
#define M_DIM 32768
#define K_DIM 1024
#define N_DIM 1024
#define E_NUM 8

#define BM 128
#define BN 128
#define BK 128            // k-bytes staged per step (full 128B cache lines)
#define KSTEPS (K_DIM / BK)   // 8

typedef __attribute__((ext_vector_type(4))) int v4i;
typedef __attribute__((ext_vector_type(4))) float v4f;

// ---------------------------------------------------------------------------
// Pass 1a: pack x (int32 valued int8) -> int8 [M][K].
// Wave-contiguous: each load instr covers 64 lanes x 16B = 1KB contiguous,
// each store 64 lanes x 4B = 256B contiguous. Grid = 8192 blocks.
// ---------------------------------------------------------------------------
__global__ __launch_bounds__(256) void pack_x_kernel(const int4* __restrict__ x,
                                                     int* __restrict__ xq) {
    const int base = blockIdx.x * 1024 + (threadIdx.x >> 6) * 256 + (threadIdx.x & 63);
#pragma unroll
    for (int k = 0; k < 4; ++k) {
        const int4 a = x[base + k * 64];
        xq[base + k * 64] =
            (a.x & 255) | ((a.y & 255) << 8) | ((a.z & 255) << 16) | (a.w << 24);
    }
}

// ---------------------------------------------------------------------------
// Pass 1b: pack + transpose weight [E][K][N] int32 -> [E][N][K] int8.
// ---------------------------------------------------------------------------
__global__ __launch_bounds__(256) void pack_wt_kernel(const int* __restrict__ w,
                                                      int* __restrict__ wt) {
    __shared__ signed char tile[64][260];   // [n][k], +4 pad keeps banks spread
    const int e    = blockIdx.z;
    const int n0   = blockIdx.x * 64;
    const int k0   = blockIdx.y * 256;
    const int tid  = threadIdx.x;
    const int lane = tid & 63;
    const int wv   = tid >> 6;

    const int* wp = w + ((size_t)e << 20);
#pragma unroll 4
    for (int i = 0; i < 64; ++i) {
        const int k = wv * 64 + i;          // each wave: 64 k-rows
        tile[lane][k] = (signed char)wp[(size_t)(k0 + k) * N_DIM + n0 + lane];
    }
    __syncthreads();

    int* wo = wt + ((size_t)e << 18);       // int units: 1MB/4 per expert
#pragma unroll
    for (int i = 0; i < 16; ++i) {
        const int n = i * 4 + wv;
        const int v = *(const int*)&tile[n][lane * 4];   // 260 % 4 == 0, aligned
        wo[(size_t)(n0 + n) * (K_DIM / 4) + (k0 >> 2) + lane] = v;
    }
}

// ---------------------------------------------------------------------------
// Pass 2: grouped int8 GEMM + fused dequant.
//  1. XCD m-stripe mapping: xcd = gid&7 owns contiguous 4096 rows, n inner
//     -> per-XCD A working set 4MB (L2-resident).
//  2. 2-deep counted-vmcnt pipeline (T3/T4): never drain vmcnt(0) in steady
//     state. Explicit lgkmcnt(0)+sched_barrier(0) before the barrier that
//     frees buffer `cur` for overwrite (rule #18).
//  3. Epilogue LDS bounce -> 512B-contiguous float4 stores.
// This is byte-identical to the round-2 source, which measured 327.2us e2e
// / 84us gmm, passed. Resubmitted to isolate infra-vs-kernel after two
// consecutive container failures on the rounds-5/6 variants.
// ---------------------------------------------------------------------------
__global__ __launch_bounds__(256, 2) void gmm_kernel(
    const signed char* __restrict__ xq,    // [M][K] int8
    const signed char* __restrict__ wtq,   // [E][N][K] int8
    const float* __restrict__ scale,       // [E][N]
    const float* __restrict__ pts,         // [M]
    const int* __restrict__ g32,           // group_list viewed as int32
    float* __restrict__ out)               // [M][N] fp32
{
    // A(b) = smem + b*16KB, B(b) = smem + 32KB + b*16KB; epilogue fp32 tile
    // reuses all 64KB.
    __shared__ signed char smem[65536];

    const int tid  = threadIdx.x;
    const int lane = tid & 63;
    const int wv   = tid >> 6;             // wave 0..3
    const int gid  = blockIdx.x;

    // XCD-stripe mapping: consecutive gids round-robin XCDs; each XCD gets
    // m-blocks [xcd*32, xcd*32+32) with n innermost.
    const int xcd   = gid & 7;
    const int local = gid >> 3;
    const int m0    = (xcd * 32 + (local >> 3)) * BM;
    const int n0    = (local & 7) * BN;

    // group_list (dtype-robust)
    const bool g_is_i64 = (g32[7] != M_DIM);
    int cum[E_NUM];
#pragma unroll
    for (int e = 0; e < E_NUM; ++e)
        cum[e] = g_is_i64 ? g32[2 * e] : g32[e];
    int e0 = 0;
    while (e0 < E_NUM - 1 && cum[e0] <= m0) ++e0;
    int e1 = 0;
    while (e1 < E_NUM - 1 && cum[e1] <= m0 + BM - 1) ++e1;

    const int wm    = (wv >> 1) * 64;
    const int wn    = (wv & 1) * 64;
    const int row_a = lane & 15;
    const int quad  = lane >> 4;
    const int rx    = row_a & 7;           // row&7 for all frag rows

    // staging lane geometry: chunk = 8 rows x 128B = 1KB, XOR-swizzled slots
    const int st_r = lane >> 3;                     // row in chunk 0..7
    const int st_c = ((lane & 7) ^ st_r) * 16;      // swizzled col bytes

    const signed char* xg = xq + (size_t)m0 * K_DIM;

    for (int e = e0; e <= e1; ++e) {
        const int lo = (e == 0) ? 0 : cum[e - 1];
        const int hi = cum[e];
        if (hi <= lo) continue;            // block-uniform
        const int slo = lo > m0 ? lo : m0;
        const int shi = hi < m0 + BM ? hi : m0 + BM;
        if (slo >= shi) continue;

        const signed char* wg = wtq + ((size_t)e << 20) + (size_t)n0 * K_DIM;

        // epilogue scalars (fly during the whole GEMM; counted-vmcnt
        // discipline below is order-robust to where these land)
        float sc[4], pt[16];
#pragma unroll
        for (int j = 0; j < 4; ++j)
            sc[j] = scale[e * N_DIM + n0 + wn + j * 16 + row_a];
#pragma unroll
        for (int i = 0; i < 4; ++i)
#pragma unroll
            for (int r = 0; r < 4; ++r)
                pt[i * 4 + r] = pts[m0 + wm + i * 16 + quad * 4 + r];

        v4i acc[4][4];
#pragma unroll
        for (int i = 0; i < 4; ++i)
#pragma unroll
            for (int j = 0; j < 4; ++j)
                acc[i][j] = (v4i){0, 0, 0, 0};

        auto stage = [&](int t, int b) {   // 8 global_load_lds per thread
            const int kb = t * BK;
            signed char* Ad = smem + b * 16384;
            signed char* Bd = smem + 32768 + b * 16384;
#pragma unroll
            for (int s = 0; s < 4; ++s) {
                const int c   = s * 4 + wv;        // chunk 0..15
                const int row = c * 8 + st_r;      // 0..127
                __builtin_amdgcn_global_load_lds(
                    (const __attribute__((address_space(1))) void*)
                        (xg + (size_t)row * K_DIM + kb + st_c),
                    (__attribute__((address_space(3))) void*)(Ad + c * 1024),
                    16, 0, 0);
                __builtin_amdgcn_global_load_lds(
                    (const __attribute__((address_space(1))) void*)
                        (wg + (size_t)row * K_DIM + kb + st_c),
                    (__attribute__((address_space(3))) void*)(Bd + c * 1024),
                    16, 0, 0);
            }
        };

        // prologue: two tiles in flight, wait only for tile 0
        stage(0, 0);
        stage(1, 1);
        asm volatile("s_waitcnt vmcnt(8)" ::: "memory");   // tile 0 landed
        __builtin_amdgcn_sched_barrier(0);
        __builtin_amdgcn_s_barrier();

        for (int t = 0; t < KSTEPS; ++t) {
            const int cur = t & 1;
            const signed char* Ab = smem + cur * 16384;
            const signed char* Bb = smem + 32768 + cur * 16384;

#pragma unroll
            for (int w = 0; w < 2; ++w) {                // two K=64 windows
                const int sa = ((w << 2) + quad) ^ rx;   // swizzled 16B slot
                v4i af[4], bf[4];
#pragma unroll
                for (int i = 0; i < 4; ++i)
                    af[i] = *(const v4i*)(Ab + (wm + i * 16 + row_a) * BK + sa * 16);
#pragma unroll
                for (int j = 0; j < 4; ++j)
                    bf[j] = *(const v4i*)(Bb + (wn + j * 16 + row_a) * BK + sa * 16);
#pragma unroll
                for (int i = 0; i < 4; ++i)
#pragma unroll
                    for (int j = 0; j < 4; ++j)
                        acc[i][j] = __builtin_amdgcn_mfma_i32_16x16x64_i8(
                            af[i], bf[j], acc[i][j], 0, 0, 0);
            }

            // drain this tile's ds_reads BEFORE freeing cur for overwrite
            // (rule #18: compiler may sink MFMA + implicit lgkm waits)
            asm volatile("s_waitcnt lgkmcnt(0)" ::: "memory");
            __builtin_amdgcn_sched_barrier(0);
            __builtin_amdgcn_s_barrier();                // all waves done w/ cur

            if (t + 2 < KSTEPS) stage(t + 2, cur);       // refill freed buffer
            if (t + 1 < KSTEPS) {
                if (t + 2 < KSTEPS)
                    asm volatile("s_waitcnt vmcnt(8)" ::: "memory"); // t+1 landed
                else
                    asm volatile("s_waitcnt vmcnt(0)" ::: "memory"); // last tile
                __builtin_amdgcn_sched_barrier(0);
                __builtin_amdgcn_s_barrier();            // visible to all waves
            }
        }

        // epilogue: dequant in registers -> LDS bounce -> 512B-contiguous
        // float4 stores (full cache lines)
        float* fs = (float*)smem;
#pragma unroll
        for (int i = 0; i < 4; ++i)
#pragma unroll
            for (int j = 0; j < 4; ++j)
#pragma unroll
                for (int r = 0; r < 4; ++r)
                    fs[(wm + i * 16 + quad * 4 + r) * BN + wn + j * 16 + row_a] =
                        (float)acc[i][j][r] * sc[j] * pt[i * 4 + r];
        asm volatile("s_waitcnt lgkmcnt(0)" ::: "memory");
        __builtin_amdgcn_sched_barrier(0);
        __builtin_amdgcn_s_barrier();

#pragma unroll
        for (int it = 0; it < 16; ++it) {
            const int idx = it * 256 + tid;      // 0..4095 float4s
            const int row = idx >> 5;            // 0..127
            const int s4  = idx & 31;
            const int rr  = m0 + row;
            if (rr >= slo && rr < shi)
                *(v4f*)(out + (size_t)rr * N_DIM + n0 + s4 * 4) =
                    *(const v4f*)(fs + row * BN + s4 * 4);
        }
        // drain fs ds_reads before next expert's stage overwrites smem
        asm volatile("s_waitcnt lgkmcnt(0)" ::: "memory");
        __builtin_amdgcn_sched_barrier(0);
        __builtin_amdgcn_s_barrier();
    }
}

// ---------------------------------------------------------------------------
extern "C" void kernel_launch(void* const* d_in, const int* in_sizes, int n_in,
                              void* d_out, int out_size, void* d_ws, size_t ws_size,
                              hipStream_t stream) {
    const int*   x     = (const int*)d_in[0];
    const int*   w     = (const int*)d_in[1];
    const float* scale = (const float*)d_in[2];
    const float* pts   = (const float*)d_in[3];
    const int*   g32   = (const int*)d_in[4];   // int32 or int64 -- sniffed in-kernel
    float*       out   = (float*)d_out;

    signed char* xq  = (signed char*)d_ws;                 // 32 MB
    signed char* wtq = xq + (size_t)M_DIM * K_DIM;         // 8 MB

    pack_x_kernel<<<M_DIM * K_DIM / 4 / 1024, 256, 0, stream>>>(
        (const int4*)x, (int*)xq);

    pack_wt_kernel<<<dim3(N_DIM / 64, K_DIM / 256, E_NUM), 256, 0, stream>>>(
        w, (int*)wtq);

    gmm_kernel<<<(M_DIM / BM) * (N_DIM / BN), 256, 0, stream>>>(
        xq, wtq, scale, pts, g32, out);
}